// Round 9
// baseline (14.644 us; speedup 1.0000x reference)
//
#include <hip/hip_runtime.h>
#include <math.h>

#define LUT_N 256
#define LUT_R 6.0f
#define CL 32
#define WARM 8
#define NSTEP (CL + WARM)
#define B_SZ 256
#define T_LEN 8192

typedef float f2 __attribute__((ext_vector_type(2)));

// Phase-split fused kernel:
//   A: G1 recurrence for all steps -> y1arr (regs)
//   B: all LUT lookups issued back-to-back (pipelined LDS latency) -> nlarr
//   C: G2 (static FIR on nlarr + y2 recurrence) + G3 + store
// CL=32/WARM=8: redundancy 1.25. 256 blocks x 256 threads = 1 wave/SIMD.
__global__ __launch_bounds__(256, 1) void wh_fused_kernel(
    const float* __restrict__ u,
    const float* __restrict__ g1b_g, const float* __restrict__ g1a_g,
    const float* __restrict__ w1_g, const float* __restrict__ b1_g,
    const float* __restrict__ w2_g, const float* __restrict__ b2_g,
    const float* __restrict__ g2b_g, const float* __restrict__ g2a_g,
    const float* __restrict__ g3b_g, const float* __restrict__ g3a_g,
    float* __restrict__ out) {
  __shared__ f2 lutP[2 * LUT_N];   // (value, delta) f32 pairs, 4 KB

  // ---- cooperative LUT build: thread tid fills entries [2*tid, 2*tid+2)
  {
    const int e0 = threadIdx.x * 2;        // both entries share one channel
    const int ch = e0 >> 8;                // 0 or 1
    const int i0 = e0 & (LUT_N - 1);
    const float LOG2E2 = 2.8853900817779268f;  // 2*log2(e)
    float k[10], c0[10], m2[10];
    float base = b2_g[ch];
#pragma unroll
    for (int h = 0; h < 10; ++h) {
      const float w1v = w1_g[ch * 10 + h];
      const float b1v = b1_g[ch * 10 + h];
      const float w2v = w2_g[ch * 10 + h];
      k[h]  = w1v * LOG2E2;
      c0[h] = b1v * LOG2E2;
      m2[h] = -2.0f * w2v;
      base += w2v;
    }
    float val[3];
#pragma unroll
    for (int j = 0; j < 3; ++j) {
      const int i = (i0 + j) > (LUT_N - 1) ? (LUT_N - 1) : (i0 + j);
      const float z = -LUT_R + (2.0f * LUT_R / (float)(LUT_N - 1)) * (float)i;
      float acc = base;
#pragma unroll
      for (int h = 0; h < 10; ++h) {
        const float e = exp2f(fmaf(z, k[h], c0[h]));       // e^{2x}; inf ok
        const float r = __builtin_amdgcn_rcpf(1.0f + e);   // 1/(1+e^{2x})
        acc = fmaf(m2[h], r, acc);
      }
      val[j] = acc;
    }
    lutP[e0]     = (f2){val[0], val[1] - val[0]};
    lutP[e0 + 1] = (f2){val[1], val[2] - val[1]};
  }
  __syncthreads();

  const int b = blockIdx.x;                 // one block per batch row
  const int c = threadIdx.x;                // chunk in [0,256)
  const float* ub = u + b * T_LEN;
  float* outp = out + b * T_LEN + c * CL;
  const int t0 = c * CL - WARM;             // multiple of 8

  // uniform coefficients -> regs (f2 packs channel pair; AR coeffs pre-negated)
  f2 g1bv[4], g1av[4], g2bv[4], g2av[4];
  float g3b[6], g3a[6];
#pragma unroll
  for (int kk = 0; kk < 4; ++kk) {
    g1bv[kk] = (f2){g1b_g[kk], g1b_g[4 + kk]};
    g1av[kk] = (f2){-g1a_g[kk], -g1a_g[4 + kk]};
    g2bv[kk] = (f2){g2b_g[kk], g2b_g[4 + kk]};
    g2av[kk] = (f2){-g2a_g[kk], -g2a_g[4 + kk]};
  }
#pragma unroll
  for (int kk = 0; kk < 6; ++kk) { g3b[kk] = g3b_g[kk]; g3a[kk] = -g3a_g[kk]; }

  // ---- u window: uarr[s] = u[t0+s] (zero for t<0), upre[k] = u[t0-1-k]
  float uarr[NSTEP];
#pragma unroll
  for (int s = 0; s < NSTEP; s += 4) {
    const int t = t0 + s;
    if (s >= WARM || t >= 0) {   // s>=WARM -> t>=0 (t0 >= -WARM)
      const float4 v = *reinterpret_cast<const float4*>(ub + t);
      uarr[s] = v.x; uarr[s + 1] = v.y; uarr[s + 2] = v.z; uarr[s + 3] = v.w;
    } else {
      uarr[s] = 0.f; uarr[s + 1] = 0.f; uarr[s + 2] = 0.f; uarr[s + 3] = 0.f;
    }
  }
  float upre[6];
  if (t0 >= 8) {
    const float4 va = *reinterpret_cast<const float4*>(ub + t0 - 8);
    const float4 vb = *reinterpret_cast<const float4*>(ub + t0 - 4);
    upre[0] = vb.w; upre[1] = vb.z; upre[2] = vb.y;
    upre[3] = vb.x; upre[4] = va.w; upre[5] = va.z;
  } else {
#pragma unroll
    for (int kk = 0; kk < 6; ++kk) upre[kk] = 0.0f;   // c==0: all t<0
  }
#define U_AT(j) (((j) >= 0) ? uarr[(j)] : upre[-1 - (j)])

  // ================= Phase A: G1 recurrence -> y1arr =================
  f2 y1arr[NSTEP];
  {
    f2 y1h[4] = {(f2)0.f, (f2)0.f, (f2)0.f, (f2)0.f};
#pragma unroll
    for (int s = 0; s < NSTEP; ++s) {
      f2 acc = g1bv[0] * (f2)U_AT(s - 1);
      acc = __builtin_elementwise_fma(g1bv[1], (f2)U_AT(s - 2), acc);
      acc = __builtin_elementwise_fma(g1bv[2], (f2)U_AT(s - 3), acc);
      acc = __builtin_elementwise_fma(g1bv[3], (f2)U_AT(s - 4), acc);
      acc = __builtin_elementwise_fma(g1av[1], y1h[1], acc);
      acc = __builtin_elementwise_fma(g1av[2], y1h[2], acc);
      acc = __builtin_elementwise_fma(g1av[3], y1h[3], acc);
      acc = __builtin_elementwise_fma(g1av[0], y1h[0], acc);  // newest last
      y1arr[s] = acc;
      y1h[3] = y1h[2]; y1h[2] = y1h[1]; y1h[1] = y1h[0]; y1h[0] = acc;
    }
  }

  // ================= Phase B: all LUT lookups (pipelined) =================
  const float lscale = (float)(LUT_N - 1) / (2.0f * LUT_R);
  const float loffs  = LUT_R * lscale;
  const float PMAX   = (float)(LUT_N - 2) + 0.999f;   // med3 upper: ii<=N-2, fr<1
  f2 nlarr[NSTEP];
#pragma unroll
  for (int s = 0; s < NSTEP; ++s) {
    const f2 pv = __builtin_elementwise_fma(y1arr[s], (f2)lscale, (f2)loffs);
    f2 nlv;
#pragma unroll
    for (int o = 0; o < 2; ++o) {
      float p = (o == 0) ? pv.x : pv.y;
      p = __builtin_amdgcn_fmed3f(p, 0.0f, PMAX);
      const int ii = (int)p;                        // p >= 0: trunc == floor
      const float fr = __builtin_amdgcn_fractf(p);  // v_fract_f32
      const f2 vd = lutP[o * LUT_N + ii];           // (value, delta)
      const float r = fmaf(fr, vd.y, vd.x);
      if (o == 0) nlv.x = r; else nlv.y = r;
    }
    if (s < WARM) {                   // t<0 only possible during warm-up
      if (t0 + s < 0) nlv = (f2)0.f;  // reference has no samples before t=0
    }
    nlarr[s] = nlv;
  }
#define NL_AT(j) (((j) >= 0) ? nlarr[(j)] : (f2)0.f)

  // ================= Phase C: G2 + G3 + store =================
  {
    f2 y2h[4] = {(f2)0.f, (f2)0.f, (f2)0.f, (f2)0.f};
    float y3h[6] = {0.f, 0.f, 0.f, 0.f, 0.f, 0.f};
    float obuf[4];
#pragma unroll
    for (int s = 0; s < NSTEP; ++s) {
      // G2 (O=1, I=2): FIR taps are static reads of nlarr
      f2 acc2 = g2bv[0] * NL_AT(s - 1);
      acc2 = __builtin_elementwise_fma(g2bv[1], NL_AT(s - 2), acc2);
      acc2 = __builtin_elementwise_fma(g2bv[2], NL_AT(s - 3), acc2);
      acc2 = __builtin_elementwise_fma(g2bv[3], NL_AT(s - 4), acc2);
      acc2 = __builtin_elementwise_fma(g2av[1], y2h[1], acc2);
      acc2 = __builtin_elementwise_fma(g2av[2], y2h[2], acc2);
      acc2 = __builtin_elementwise_fma(g2av[3], y2h[3], acc2);
      acc2 = __builtin_elementwise_fma(g2av[0], y2h[0], acc2);
      y2h[3] = y2h[2]; y2h[2] = y2h[1]; y2h[1] = y2h[0]; y2h[0] = acc2;

      // G3 (O=1, I=1, nb=na=6) on u
      float acc3 = g3b[0] * U_AT(s - 1);
      acc3 = fmaf(g3b[1], U_AT(s - 2), acc3);
      acc3 = fmaf(g3b[2], U_AT(s - 3), acc3);
      acc3 = fmaf(g3b[3], U_AT(s - 4), acc3);
      acc3 = fmaf(g3b[4], U_AT(s - 5), acc3);
      acc3 = fmaf(g3b[5], U_AT(s - 6), acc3);
      acc3 = fmaf(g3a[1], y3h[1], acc3);
      acc3 = fmaf(g3a[2], y3h[2], acc3);
      acc3 = fmaf(g3a[3], y3h[3], acc3);
      acc3 = fmaf(g3a[4], y3h[4], acc3);
      acc3 = fmaf(g3a[5], y3h[5], acc3);
      acc3 = fmaf(g3a[0], y3h[0], acc3);
      y3h[5] = y3h[4]; y3h[4] = y3h[3]; y3h[3] = y3h[2];
      y3h[2] = y3h[1]; y3h[1] = y3h[0]; y3h[0] = acc3;

      const float yo = acc2.x + acc2.y + acc3;

      if (s >= WARM) {
        obuf[(s - WARM) & 3] = yo;
        if (((s - WARM) & 3) == 3) {
          float4 v;
          v.x = obuf[0]; v.y = obuf[1]; v.z = obuf[2]; v.w = obuf[3];
          *reinterpret_cast<float4*>(outp + (s - WARM - 3)) = v;
        }
      }
    }
  }
#undef U_AT
#undef NL_AT
}

extern "C" void kernel_launch(void* const* d_in, const int* in_sizes, int n_in,
                              void* d_out, int out_size, void* d_ws, size_t ws_size,
                              hipStream_t stream) {
  const float* u   = (const float*)d_in[0];
  const float* g1b = (const float*)d_in[1];
  const float* g1a = (const float*)d_in[2];
  const float* w1  = (const float*)d_in[3];
  const float* b1  = (const float*)d_in[4];
  const float* w2  = (const float*)d_in[5];
  const float* b2  = (const float*)d_in[6];
  const float* g2b = (const float*)d_in[7];
  const float* g2a = (const float*)d_in[8];
  const float* g3b = (const float*)d_in[9];
  const float* g3a = (const float*)d_in[10];
  float* out = (float*)d_out;

  wh_fused_kernel<<<dim3(B_SZ), dim3(256), 0, stream>>>(
      u, g1b, g1a, w1, b1, w2, b2, g2b, g2a, g3b, g3a, out);
}